// Round 1
// baseline (4275.874 us; speedup 1.0000x reference)
//
#include <hip/hip_runtime.h>

// GRU encoder: B=64, T=256, U=1024, VOCAB=10000. All float tensors are FP32.
// GEMM on bf16 MFMA (RNE-converted inputs); h carry stays exact f32 in a
// per-thread register. This version replaces 256 per-step launches with ONE
// persistent kernel: W_rec fragments live in VGPRs for the whole sequence,
// and steps are separated by a custom 64-block barrier per batch-rowgroup.
#define BB 64
#define TT 256
#define UU 1024
#define NG 3072

typedef __attribute__((ext_vector_type(8))) __bf16 bf16x8;
typedef __attribute__((ext_vector_type(4))) float f32x4;

__device__ __forceinline__ unsigned short f2bf(float f) {
    union { unsigned int i; float f; } c; c.f = f;
    unsigned int r = c.i + 0x7FFFu + ((c.i >> 16) & 1u);  // RNE
    return (unsigned short)(r >> 16);
}

union U16x8 { unsigned short us[8]; uint4 u4; };

// ---------------------------------------------------------------------------
// Pack W_rec (f32) into bf16 MFMA B-fragment order (unchanged from the
// verified kernel). Total 6 MB.
// ---------------------------------------------------------------------------
__global__ __launch_bounds__(256) void pack_kernel(
    const float* __restrict__ w_rec,    // (1024, 3072) f32
    uint4* __restrict__ wpack)
{
    const int tid  = threadIdx.x;
    const int kc   = tid >> 6;
    const int lane = tid & 63;
    const int l16  = lane & 15;
    const int quad = lane >> 4;
    const int cj   = blockIdx.x;            // 0..63
    const int colb = (cj << 4) + l16;

    #pragma unroll
    for (int g = 0; g < 3; ++g) {
        #pragma unroll
        for (int s = 0; s < 8; ++s) {
            const int kb = (kc << 8) + (s << 5) + (quad << 3);
            U16x8 c;
            #pragma unroll
            for (int j = 0; j < 8; ++j)
                c.us[j] = f2bf(w_rec[(size_t)(kb + j) * NG + g * UU + colb]);
            wpack[(size_t)(((cj * 4 + kc) * 24) + g * 8 + s) * 64 + lane] = c.u4;
        }
    }
}

// Seed: f32 hidden -> bf16 exchange buffer parity 0, and reset the barrier
// counters (graph replays re-run this, so each launch starts clean).
__global__ __launch_bounds__(256) void seed_kernel(
    const float* __restrict__ hidden,       // (64, 1024) f32
    unsigned short* __restrict__ hbuf,
    unsigned int* __restrict__ ctr)
{
    const int i = blockIdx.x * 256 + threadIdx.x;   // 65536 elements
    hbuf[i] = f2bf(hidden[i]);
    if (i < 128) ctr[i] = 0u;                       // 4 counters, 32-uint stride
}

// ---------------------------------------------------------------------------
// Persistent GRU kernel. 256 blocks x 256 threads, 1 block/CU.
// block = (ri, cj): ri = batch rowgroup (4 x 16 rows), cj = unit colgroup
// (64 x 16 cols). Waves K-split (4 x 256). W fragments resident in VGPRs.
// Step t+1 of rowgroup ri depends only on the 64 blocks sharing ri, so each
// ri has its own 64-block release/acquire barrier. hbuf is double-buffered
// by step parity so a fast block cannot overwrite a buffer a slow block in
// its group is still reading.
// ---------------------------------------------------------------------------
__global__ __launch_bounds__(256) void gru_kernel(
    const int* __restrict__ x,              // (64, 256) int32
    const float* __restrict__ hidden,       // (64, 1024) f32
    const float* __restrict__ w_in,         // (10000, 3072) f32
    const float* __restrict__ b_in,         // (3072,) f32
    const float* __restrict__ b_rec,        // (3072,) f32
    const uint4* __restrict__ wpack,        // packed W_rec bf16 frags
    float* __restrict__ out,                // (64,256,1024) + (64,1024) f32
    unsigned short* __restrict__ hbuf,      // ws: 2 x 64 x 1024 bf16 exchange
    unsigned int* __restrict__ ctr)         // ws: 4 barrier counters
{
    const int tid  = threadIdx.x;
    const int wave = tid >> 6;        // K-chunk 0..3
    const int lane = tid & 63;
    const int l16  = lane & 15;
    const int quad = lane >> 4;

    const int ri   = blockIdx.x >> 6;  // 0..3
    const int cj   = blockIdx.x & 63;  // 0..63
    const int row0 = ri << 4;
    const int col0 = cj << 4;

    __align__(16) __shared__ float red[4][3][64][4];   // 12 KB

    // ---- B-fragments: loaded ONCE, resident in 96 VGPRs for all 256 steps.
    const uint4* wp = wpack + (size_t)((cj * 4 + wave) * 24) * 64 + lane;
    uint4 wf[3][8];
    #pragma unroll
    for (int g = 0; g < 3; ++g)
        #pragma unroll
        for (int s = 0; s < 8; ++s)
            wf[g][s] = wp[(g * 8 + s) * 64];

    // ---- per-thread gate element (fixed for the whole sequence) ----
    const int em = tid >> 4;
    const int en = tid & 15;
    const int gb = row0 + em;
    const int gu = col0 + en;
    // C/D layout (col=lane&15, row=(lane>>4)*4+reg) -> source lane/reg
    const int rl = ((em >> 2) << 4) | en;
    const int rr = em & 3;

    // loop-invariant biases
    const float bz  = b_in[gu]          + b_rec[gu];
    const float br  = b_in[UU + gu]     + b_rec[UU + gu];
    const float bih = b_in[2 * UU + gu];
    const float brh = b_rec[2 * UU + gu];

    // exact f32 h carry in a register
    float h = hidden[gb * UU + gu];

    const int* xrow = x + gb * TT;
    unsigned int* myc = ctr + ri * 32;          // 128 B apart: no false sharing

    const unsigned short* ab0 = hbuf + (size_t)(row0 + l16) * UU
                              + (wave << 8) + (quad << 3);     // parity 0 A base
    const unsigned short* ab1 = ab0 + (size_t)BB * UU;          // parity 1
    unsigned short* hb0 = hbuf + (size_t)gb * UU + gu;          // parity 0 h slot
    unsigned short* hb1 = hb0 + (size_t)BB * UU;                // parity 1
    float* orow = out + (size_t)gb * TT * UU + gu;

    for (int t = 0; t < TT; ++t) {
        // ---- embedding gather issued early; consumed after the GEMM ----
        const size_t wrow = (size_t)xrow[t] * NG;
        const float wz = w_in[wrow + gu];
        const float wr = w_in[wrow + UU + gu];
        const float wh = w_in[wrow + 2 * UU + gu];

        // ---- A from bf16 exchange buffer, parity t&1 ----
        const unsigned short* arow = (t & 1) ? ab1 : ab0;
        f32x4 acc0 = {0.f, 0.f, 0.f, 0.f};
        f32x4 acc1 = {0.f, 0.f, 0.f, 0.f};
        f32x4 acc2 = {0.f, 0.f, 0.f, 0.f};
        #pragma unroll
        for (int s = 0; s < 8; ++s) {
            const uint4 av = *(const uint4*)(arow + (s << 5));
            const bf16x8 a = __builtin_bit_cast(bf16x8, av);
            acc0 = __builtin_amdgcn_mfma_f32_16x16x32_bf16(
                a, __builtin_bit_cast(bf16x8, wf[0][s]), acc0, 0, 0, 0);
            acc1 = __builtin_amdgcn_mfma_f32_16x16x32_bf16(
                a, __builtin_bit_cast(bf16x8, wf[1][s]), acc1, 0, 0, 0);
            acc2 = __builtin_amdgcn_mfma_f32_16x16x32_bf16(
                a, __builtin_bit_cast(bf16x8, wf[2][s]), acc2, 0, 0, 0);
        }

        // ---- cross-wave K reduction through LDS ----
        *(f32x4*)&red[wave][0][lane][0] = acc0;
        *(f32x4*)&red[wave][1][lane][0] = acc1;
        *(f32x4*)&red[wave][2][lane][0] = acc2;
        __syncthreads();

        const float rz = red[0][0][rl][rr] + red[1][0][rl][rr]
                       + red[2][0][rl][rr] + red[3][0][rl][rr];
        const float rrv = red[0][1][rl][rr] + red[1][1][rl][rr]
                        + red[2][1][rl][rr] + red[3][1][rl][rr];
        const float rh = red[0][2][rl][rr] + red[1][2][rl][rr]
                       + red[2][2][rl][rr] + red[3][2][rl][rr];

        const float z  = 1.f / (1.f + expf(-(wz + rz + bz)));
        const float r  = 1.f / (1.f + expf(-(wr + rrv + br)));
        const float hh = tanhf(wh + bih + r * (rh + brh));
        h = z * h + (1.f - z) * hh;

        orow[(size_t)t * UU] = h;

        if (t < TT - 1) {
            // publish h_t (parity (t+1)&1) for the next step's A-operand
            *((t & 1) ? hb0 : hb1) = f2bf(h);

            // (2) drain this block's stores to L2 (syncthreads waits vmcnt(0))
            __syncthreads();
            // release: tid0's agent-scope RMW writes back this XCD's L2 so
            // hbuf lines reach the device-coherent point before the count
            if (tid == 0)
                __hip_atomic_fetch_add(myc, 1u, __ATOMIC_RELEASE,
                                       __HIP_MEMORY_SCOPE_AGENT);
            // wave 0 spins; waves 1-3 held at the barrier below
            if (tid < 64) {
                const unsigned int target = (unsigned int)(t + 1) << 6; // 64 blks
                while (__hip_atomic_load(myc, __ATOMIC_RELAXED,
                                         __HIP_MEMORY_SCOPE_AGENT) < target) {}
            }
            __syncthreads();
            // acquire: invalidate L1 + stale remote L2 lines before reading
            // the hbuf parity buffer written by the other 63 blocks
            __builtin_amdgcn_fence(__ATOMIC_ACQUIRE, "agent");
        }
    }

    // final state
    out[(size_t)BB * TT * UU + (size_t)gb * UU + gu] = h;
}

extern "C" void kernel_launch(void* const* d_in, const int* in_sizes, int n_in,
                              void* d_out, int out_size, void* d_ws, size_t ws_size,
                              hipStream_t stream) {
    const int* x        = (const int*)d_in[0];
    const float* hidden = (const float*)d_in[1];
    const float* w_in   = (const float*)d_in[2];
    const float* w_rec  = (const float*)d_in[3];
    const float* b_in   = (const float*)d_in[4];
    const float* b_rec  = (const float*)d_in[5];
    float* out          = (float*)d_out;

    unsigned char* ws = (unsigned char*)d_ws;
    uint4* wpack         = (uint4*)ws;                         // 6 MB
    unsigned short* hbuf = (unsigned short*)(ws + 6291456);    // 256 KB
    unsigned int* ctr    = (unsigned int*)(ws + 6553600);      // 512 B

    pack_kernel<<<64, 256, 0, stream>>>(w_rec, wpack);
    seed_kernel<<<256, 256, 0, stream>>>(hidden, hbuf, ctr);
    gru_kernel<<<256, 256, 0, stream>>>(x, hidden, w_in, b_in, b_rec,
                                        wpack, out, hbuf, ctr);
}

// Round 2
// 1767.189 us; speedup vs baseline: 2.4196x; 2.4196x over previous
//
#include <hip/hip_runtime.h>

// GRU encoder: B=64, T=256, U=1024, VOCAB=10000. All float tensors are FP32.
// GEMM on bf16 MFMA (RNE-converted inputs); h carry stays exact f32 in a
// per-thread register. ONE persistent kernel; W_rec fragments resident in
// registers for all 256 steps. Cross-block step barrier is FENCE-FREE:
// all cross-block data (hbuf h-exchange, flags) moves with sc0 sc1
// write-through stores / coherent loads at the LLC, so no buffer_wbl2 /
// buffer_inv per step (round-1's 16 us/step stall) and the L2 keeps w_in
// cached across steps.
#define BB 64
#define TT 256
#define UU 1024
#define NG 3072

typedef __attribute__((ext_vector_type(8))) __bf16 bf16x8;
typedef __attribute__((ext_vector_type(4))) float f32x4;

__device__ __forceinline__ unsigned short f2bf(float f) {
    union { unsigned int i; float f; } c; c.f = f;
    unsigned int r = c.i + 0x7FFFu + ((c.i >> 16) & 1u);  // RNE
    return (unsigned short)(r >> 16);
}

union U16x8 { unsigned short us[8]; uint4 u4; };

// ---------------------------------------------------------------------------
// Pack W_rec (f32) into bf16 MFMA B-fragment order (unchanged, verified).
// Total 6 MB.
// ---------------------------------------------------------------------------
__global__ __launch_bounds__(256) void pack_kernel(
    const float* __restrict__ w_rec,    // (1024, 3072) f32
    uint4* __restrict__ wpack)
{
    const int tid  = threadIdx.x;
    const int kc   = tid >> 6;
    const int lane = tid & 63;
    const int l16  = lane & 15;
    const int quad = lane >> 4;
    const int cj   = blockIdx.x;            // 0..63
    const int colb = (cj << 4) + l16;

    #pragma unroll
    for (int g = 0; g < 3; ++g) {
        #pragma unroll
        for (int s = 0; s < 8; ++s) {
            const int kb = (kc << 8) + (s << 5) + (quad << 3);
            U16x8 c;
            #pragma unroll
            for (int j = 0; j < 8; ++j)
                c.us[j] = f2bf(w_rec[(size_t)(kb + j) * NG + g * UU + colb]);
            wpack[(size_t)(((cj * 4 + kc) * 24) + g * 8 + s) * 64 + lane] = c.u4;
        }
    }
}

// Seed: f32 hidden -> bf16 exchange buffer parity 0; reset the 256 step flags
// (graph replays re-run this, so each launch starts clean). Kernel-end flush
// makes these visible at the LLC for gru's sc1 reads.
__global__ __launch_bounds__(256) void seed_kernel(
    const float* __restrict__ hidden,       // (64, 1024) f32
    unsigned short* __restrict__ hbuf,
    unsigned int* __restrict__ ctr)
{
    const int i = blockIdx.x * 256 + threadIdx.x;   // 65536 elements
    hbuf[i] = f2bf(hidden[i]);
    if (i < 256) ctr[i] = 0u;                       // 4 groups x 64 flags
}

// ---------------------------------------------------------------------------
// Persistent GRU kernel. 256 blocks x 256 threads, 1 block/CU.
// block = (ri, cj): ri = batch rowgroup (4 x 16 rows), cj = unit colgroup
// (64 x 16 cols). Waves K-split (4 x 256). Step t+1 of rowgroup ri depends
// only on the 64 blocks sharing ri -> per-group 64-flag barrier. hbuf is
// double-buffered by step parity.
// ---------------------------------------------------------------------------
__global__ __launch_bounds__(256) void gru_kernel(
    const int* __restrict__ x,              // (64, 256) int32
    const float* __restrict__ hidden,       // (64, 1024) f32
    const float* __restrict__ w_in,         // (10000, 3072) f32
    const float* __restrict__ b_in,         // (3072,) f32
    const float* __restrict__ b_rec,        // (3072,) f32
    const uint4* __restrict__ wpack,        // packed W_rec bf16 frags
    float* __restrict__ out,                // (64,256,1024) + (64,1024) f32
    unsigned short* __restrict__ hbuf,      // ws: 2 x 64 x 1024 bf16 exchange
    unsigned int* __restrict__ ctr)         // ws: 256 step flags
{
    const int tid  = threadIdx.x;
    const int wave = tid >> 6;        // K-chunk 0..3
    const int lane = tid & 63;
    const int l16  = lane & 15;
    const int quad = lane >> 4;

    const int ri   = blockIdx.x >> 6;  // 0..3
    const int cj   = blockIdx.x & 63;  // 0..63
    const int row0 = ri << 4;
    const int col0 = cj << 4;

    __align__(16) __shared__ float red[4][3][64][4];   // 12 KB

    // ---- B-fragments: loaded ONCE, resident for all 256 steps ----
    const uint4* wp = wpack + (size_t)((cj * 4 + wave) * 24) * 64 + lane;
    uint4 wf[3][8];
    #pragma unroll
    for (int g = 0; g < 3; ++g)
        #pragma unroll
        for (int s = 0; s < 8; ++s)
            wf[g][s] = wp[(g * 8 + s) * 64];

    // ---- per-thread gate element (fixed for the whole sequence) ----
    const int em = tid >> 4;
    const int en = tid & 15;
    const int gb = row0 + em;
    const int gu = col0 + en;
    // C/D layout (col=lane&15, row=(lane>>4)*4+reg) -> source lane/reg
    const int rl = ((em >> 2) << 4) | en;
    const int rr = em & 3;

    // loop-invariant biases
    const float bz  = b_in[gu]          + b_rec[gu];
    const float br  = b_in[UU + gu]     + b_rec[UU + gu];
    const float bih = b_in[2 * UU + gu];
    const float brh = b_rec[2 * UU + gu];

    // exact f32 h carry in a register
    float h = hidden[gb * UU + gu];

    const int* xrow = x + gb * TT;
    unsigned int* flg = ctr + ri * 64;      // this group's 64 flags (256 B)

    const unsigned short* ab0 = hbuf + (size_t)(row0 + l16) * UU
                              + (wave << 8) + (quad << 3);      // parity 0 A base
    const unsigned short* ab1 = ab0 + (size_t)BB * UU;          // parity 1
    unsigned short* hb0 = hbuf + (size_t)gb * UU + gu;          // parity 0 h slot
    unsigned short* hb1 = hb0 + (size_t)BB * UU;                // parity 1
    float* orow = out + (size_t)gb * TT * UU + gu;

    // embedding gather for t=0 (plain cached loads)
    size_t wrow = (size_t)xrow[0] * NG;
    float wz = w_in[wrow + gu];
    float wr = w_in[wrow + UU + gu];
    float wh = w_in[wrow + 2 * UU + gu];

    for (int t = 0; t < TT; ++t) {
        // ---- A from bf16 exchange, parity t&1: coherent LLC reads (sc0 sc1
        // bypass stale L1/L2), all 8 in flight, then one drain ----
        const unsigned short* arow = (t & 1) ? ab1 : ab0;
        uint4 av[8];
        #pragma unroll
        for (int s = 0; s < 8; ++s)
            asm volatile("global_load_dwordx4 %0, %1, off sc0 sc1"
                         : "=v"(av[s]) : "v"(arow + (s << 5)));
        asm volatile("s_waitcnt vmcnt(0)" ::: "memory");
        __builtin_amdgcn_sched_barrier(0);          // rule 18: pin MFMAs after

        f32x4 acc0 = {0.f, 0.f, 0.f, 0.f};
        f32x4 acc1 = {0.f, 0.f, 0.f, 0.f};
        f32x4 acc2 = {0.f, 0.f, 0.f, 0.f};
        #pragma unroll
        for (int s = 0; s < 8; ++s) {
            const bf16x8 a = __builtin_bit_cast(bf16x8, av[s]);
            acc0 = __builtin_amdgcn_mfma_f32_16x16x32_bf16(
                a, __builtin_bit_cast(bf16x8, wf[0][s]), acc0, 0, 0, 0);
            acc1 = __builtin_amdgcn_mfma_f32_16x16x32_bf16(
                a, __builtin_bit_cast(bf16x8, wf[1][s]), acc1, 0, 0, 0);
            acc2 = __builtin_amdgcn_mfma_f32_16x16x32_bf16(
                a, __builtin_bit_cast(bf16x8, wf[2][s]), acc2, 0, 0, 0);
        }

        // ---- cross-wave K reduction through LDS ----
        *(f32x4*)&red[wave][0][lane][0] = acc0;
        *(f32x4*)&red[wave][1][lane][0] = acc1;
        *(f32x4*)&red[wave][2][lane][0] = acc2;
        __syncthreads();

        const float rz = red[0][0][rl][rr] + red[1][0][rl][rr]
                       + red[2][0][rl][rr] + red[3][0][rl][rr];
        const float rrv = red[0][1][rl][rr] + red[1][1][rl][rr]
                        + red[2][1][rl][rr] + red[3][1][rl][rr];
        const float rh = red[0][2][rl][rr] + red[1][2][rl][rr]
                       + red[2][2][rl][rr] + red[3][2][rl][rr];

        const float z  = 1.f / (1.f + expf(-(wz + rz + bz)));
        const float r  = 1.f / (1.f + expf(-(wr + rrv + br)));
        const float hh = tanhf(wh + bih + r * (rh + brh));
        h = z * h + (1.f - z) * hh;

        orow[(size_t)t * UU] = h;

        if (t < TT - 1) {
            // prefetch next step's embedding row (hides LLC/HBM latency
            // under the barrier; consumed only after the spin)
            wrow = (size_t)xrow[t + 1] * NG;
            wz = w_in[wrow + gu];
            wr = w_in[wrow + UU + gu];
            wh = w_in[wrow + 2 * UU + gu];

            // publish h_t (parity (t+1)&1): write-through to LLC, no wbl2
            const unsigned int hv = f2bf(h);
            unsigned short* hs = (t & 1) ? hb0 : hb1;
            asm volatile("global_store_short %0, %1, off sc0 sc1"
                         :: "v"(hs), "v"(hv) : "memory");
            // drain own stores (incl. the asm one) before signaling
            asm volatile("s_waitcnt vmcnt(0)" ::: "memory");
            __syncthreads();

            // signal: own flag slot, plain coherent store -> zero contention
            if (tid == 0) {
                const unsigned int want = (unsigned int)(t + 1);
                asm volatile("global_store_dword %0, %1, off sc0 sc1"
                             :: "v"(flg + cj), "v"(want) : "memory");
            }
            // wave 0: each lane polls one of the group's 64 flags (coherent
            // agent loads). Waves 1-3 wait at the barrier below.
            if (tid < 64) {
                const unsigned int want = (unsigned int)(t + 1);
                while (__hip_atomic_load(&flg[tid], __ATOMIC_RELAXED,
                                         __HIP_MEMORY_SCOPE_AGENT) < want) {}
            }
            __syncthreads();
        }
    }

    // final state
    out[(size_t)BB * TT * UU + (size_t)gb * UU + gu] = h;
}

extern "C" void kernel_launch(void* const* d_in, const int* in_sizes, int n_in,
                              void* d_out, int out_size, void* d_ws, size_t ws_size,
                              hipStream_t stream) {
    const int* x        = (const int*)d_in[0];
    const float* hidden = (const float*)d_in[1];
    const float* w_in   = (const float*)d_in[2];
    const float* w_rec  = (const float*)d_in[3];
    const float* b_in   = (const float*)d_in[4];
    const float* b_rec  = (const float*)d_in[5];
    float* out          = (float*)d_out;

    unsigned char* ws = (unsigned char*)d_ws;
    uint4* wpack         = (uint4*)ws;                         // 6 MB
    unsigned short* hbuf = (unsigned short*)(ws + 6291456);    // 256 KB
    unsigned int* ctr    = (unsigned int*)(ws + 6553600);      // 1 KB flags

    pack_kernel<<<64, 256, 0, stream>>>(w_rec, wpack);
    seed_kernel<<<256, 256, 0, stream>>>(hidden, hbuf, ctr);
    gru_kernel<<<256, 256, 0, stream>>>(x, hidden, w_in, b_in, b_rec,
                                        wpack, out, hbuf, ctr);
}

// Round 3
// 1082.202 us; speedup vs baseline: 3.9511x; 1.6330x over previous
//
#include <hip/hip_runtime.h>

// GRU encoder: B=64, T=256, U=1024, VOCAB=10000. All float tensors are FP32.
// GEMM on bf16 MFMA (RNE-converted inputs); h carry stays exact f32 in a
// per-thread register. ONE persistent kernel; W_rec fragments resident in
// registers for all 256 steps. Cross-block step barrier is fence-free via
// sc0 sc1 (LLC-coherent) accesses. Round-3 change: the pre-signal drain
// covers ONLY the h-publish store — the out-row store and the next-step
// embedding gather are issued AFTER the signal, inside the spin window,
// so their HBM latency overlaps the barrier instead of preceding it.
#define BB 64
#define TT 256
#define UU 1024
#define NG 3072

typedef __attribute__((ext_vector_type(8))) __bf16 bf16x8;
typedef __attribute__((ext_vector_type(4))) float f32x4;

__device__ __forceinline__ unsigned short f2bf(float f) {
    union { unsigned int i; float f; } c; c.f = f;
    unsigned int r = c.i + 0x7FFFu + ((c.i >> 16) & 1u);  // RNE
    return (unsigned short)(r >> 16);
}

union U16x8 { unsigned short us[8]; uint4 u4; };

// ---------------------------------------------------------------------------
// Pack W_rec (f32) into bf16 MFMA B-fragment order (unchanged, verified).
// Total 6 MB.
// ---------------------------------------------------------------------------
__global__ __launch_bounds__(256) void pack_kernel(
    const float* __restrict__ w_rec,    // (1024, 3072) f32
    uint4* __restrict__ wpack)
{
    const int tid  = threadIdx.x;
    const int kc   = tid >> 6;
    const int lane = tid & 63;
    const int l16  = lane & 15;
    const int quad = lane >> 4;
    const int cj   = blockIdx.x;            // 0..63
    const int colb = (cj << 4) + l16;

    #pragma unroll
    for (int g = 0; g < 3; ++g) {
        #pragma unroll
        for (int s = 0; s < 8; ++s) {
            const int kb = (kc << 8) + (s << 5) + (quad << 3);
            U16x8 c;
            #pragma unroll
            for (int j = 0; j < 8; ++j)
                c.us[j] = f2bf(w_rec[(size_t)(kb + j) * NG + g * UU + colb]);
            wpack[(size_t)(((cj * 4 + kc) * 24) + g * 8 + s) * 64 + lane] = c.u4;
        }
    }
}

// Seed: f32 hidden -> bf16 exchange buffer parity 0; reset the 256 step flags
// (graph replays re-run this, so each launch starts clean).
__global__ __launch_bounds__(256) void seed_kernel(
    const float* __restrict__ hidden,       // (64, 1024) f32
    unsigned short* __restrict__ hbuf,
    unsigned int* __restrict__ ctr)
{
    const int i = blockIdx.x * 256 + threadIdx.x;   // 65536 elements
    hbuf[i] = f2bf(hidden[i]);
    if (i < 256) ctr[i] = 0u;                       // 4 groups x 64 flags
}

// ---------------------------------------------------------------------------
// Persistent GRU kernel. 256 blocks x 256 threads, 1 block/CU.
// block = (ri, cj): ri = batch rowgroup (4 x 16 rows), cj = unit colgroup
// (64 x 16 cols). Waves K-split (4 x 256). Step t+1 of rowgroup ri depends
// only on the 64 blocks sharing ri -> per-group 64-flag barrier. hbuf is
// double-buffered by step parity.
// ---------------------------------------------------------------------------
__global__ __launch_bounds__(256) void gru_kernel(
    const int* __restrict__ x,              // (64, 256) int32
    const float* __restrict__ hidden,       // (64, 1024) f32
    const float* __restrict__ w_in,         // (10000, 3072) f32
    const float* __restrict__ b_in,         // (3072,) f32
    const float* __restrict__ b_rec,        // (3072,) f32
    const uint4* __restrict__ wpack,        // packed W_rec bf16 frags
    float* __restrict__ out,                // (64,256,1024) + (64,1024) f32
    unsigned short* __restrict__ hbuf,      // ws: 2 x 64 x 1024 bf16 exchange
    unsigned int* __restrict__ ctr)         // ws: 256 step flags
{
    const int tid  = threadIdx.x;
    const int wave = tid >> 6;        // K-chunk 0..3
    const int lane = tid & 63;
    const int l16  = lane & 15;
    const int quad = lane >> 4;

    const int ri   = blockIdx.x >> 6;  // 0..3
    const int cj   = blockIdx.x & 63;  // 0..63
    const int row0 = ri << 4;
    const int col0 = cj << 4;

    __align__(16) __shared__ float red[4][3][64][4];   // 12 KB

    // ---- B-fragments: loaded ONCE, resident for all 256 steps ----
    const uint4* wp = wpack + (size_t)((cj * 4 + wave) * 24) * 64 + lane;
    uint4 wf[3][8];
    #pragma unroll
    for (int g = 0; g < 3; ++g)
        #pragma unroll
        for (int s = 0; s < 8; ++s)
            wf[g][s] = wp[(g * 8 + s) * 64];

    // ---- per-thread gate element (fixed for the whole sequence) ----
    const int em = tid >> 4;
    const int en = tid & 15;
    const int gb = row0 + em;
    const int gu = col0 + en;
    // C/D layout (col=lane&15, row=(lane>>4)*4+reg) -> source lane/reg
    const int rl = ((em >> 2) << 4) | en;
    const int rr = em & 3;

    // loop-invariant biases
    const float bz  = b_in[gu]          + b_rec[gu];
    const float br  = b_in[UU + gu]     + b_rec[UU + gu];
    const float bih = b_in[2 * UU + gu];
    const float brh = b_rec[2 * UU + gu];

    // exact f32 h carry in a register
    float h = hidden[gb * UU + gu];

    const int* xrow = x + gb * TT;
    unsigned int* flg = ctr + ri * 64;      // this group's 64 flags (256 B)

    const unsigned short* ab0 = hbuf + (size_t)(row0 + l16) * UU
                              + (wave << 8) + (quad << 3);      // parity 0 A base
    const unsigned short* ab1 = ab0 + (size_t)BB * UU;          // parity 1
    unsigned short* hb0 = hbuf + (size_t)gb * UU + gu;          // parity 0 h slot
    unsigned short* hb1 = hb0 + (size_t)BB * UU;                // parity 1
    float* orow = out + (size_t)gb * TT * UU + gu;

    // embedding gather for t=0 (plain cached loads)
    size_t wrow = (size_t)xrow[0] * NG;
    float wz = w_in[wrow + gu];
    float wr = w_in[wrow + UU + gu];
    float wh = w_in[wrow + 2 * UU + gu];

    for (int t = 0; t < TT; ++t) {
        // ---- A from bf16 exchange, parity t&1: coherent LLC reads (sc0 sc1
        // bypass stale L1/L2), all 8 in flight, then one drain. This vmcnt(0)
        // also retires the previous spin-window traffic (out store + embedding
        // prefetch), so the pre-signal drain below sees only the h store. ----
        const unsigned short* arow = (t & 1) ? ab1 : ab0;
        uint4 av[8];
        #pragma unroll
        for (int s = 0; s < 8; ++s)
            asm volatile("global_load_dwordx4 %0, %1, off sc0 sc1"
                         : "=v"(av[s]) : "v"(arow + (s << 5)));
        asm volatile("s_waitcnt vmcnt(0)" ::: "memory");
        __builtin_amdgcn_sched_barrier(0);          // rule 18: pin MFMAs after

        f32x4 acc0 = {0.f, 0.f, 0.f, 0.f};
        f32x4 acc1 = {0.f, 0.f, 0.f, 0.f};
        f32x4 acc2 = {0.f, 0.f, 0.f, 0.f};
        #pragma unroll
        for (int s = 0; s < 8; ++s) {
            const bf16x8 a = __builtin_bit_cast(bf16x8, av[s]);
            acc0 = __builtin_amdgcn_mfma_f32_16x16x32_bf16(
                a, __builtin_bit_cast(bf16x8, wf[0][s]), acc0, 0, 0, 0);
            acc1 = __builtin_amdgcn_mfma_f32_16x16x32_bf16(
                a, __builtin_bit_cast(bf16x8, wf[1][s]), acc1, 0, 0, 0);
            acc2 = __builtin_amdgcn_mfma_f32_16x16x32_bf16(
                a, __builtin_bit_cast(bf16x8, wf[2][s]), acc2, 0, 0, 0);
        }

        // ---- cross-wave K reduction through LDS ----
        *(f32x4*)&red[wave][0][lane][0] = acc0;
        *(f32x4*)&red[wave][1][lane][0] = acc1;
        *(f32x4*)&red[wave][2][lane][0] = acc2;
        __syncthreads();

        const float rz = red[0][0][rl][rr] + red[1][0][rl][rr]
                       + red[2][0][rl][rr] + red[3][0][rl][rr];
        const float rrv = red[0][1][rl][rr] + red[1][1][rl][rr]
                        + red[2][1][rl][rr] + red[3][1][rl][rr];
        const float rh = red[0][2][rl][rr] + red[1][2][rl][rr]
                       + red[2][2][rl][rr] + red[3][2][rl][rr];

        const float z  = 1.f / (1.f + expf(-(wz + rz + bz)));
        const float r  = 1.f / (1.f + expf(-(wr + rrv + br)));
        const float hh = tanhf(wh + bih + r * (rh + brh));
        h = z * h + (1.f - z) * hh;

        if (t < TT - 1) {
            // ---- publish h_t (parity (t+1)&1) FIRST: write-through to LLC.
            // Only this store is outstanding, so the drain is minimal. ----
            const unsigned int hv = f2bf(h);
            unsigned short* hs = (t & 1) ? hb0 : hb1;
            asm volatile("global_store_short %0, %1, off sc0 sc1"
                         :: "v"(hs), "v"(hv) : "memory");
            asm volatile("s_waitcnt vmcnt(0)" ::: "memory");
            __syncthreads();

            // signal: own flag slot, plain coherent store -> zero contention
            if (tid == 0) {
                const unsigned int want = (unsigned int)(t + 1);
                asm volatile("global_store_dword %0, %1, off sc0 sc1"
                             :: "v"(flg + cj), "v"(want) : "memory");
            }

            // ---- spin-window work: overlap HBM latency with the barrier ----
            orow[(size_t)t * UU] = h;                 // out row (write-back)
            wrow = (size_t)xrow[t + 1] * NG;          // next embedding gather
            wz = w_in[wrow + gu];
            wr = w_in[wrow + UU + gu];
            wh = w_in[wrow + 2 * UU + gu];

            // wave 0: each lane polls one of the group's 64 flags (coherent
            // agent loads). Waves 1-3 wait at the barrier below.
            if (tid < 64) {
                const unsigned int want = (unsigned int)(t + 1);
                while (__hip_atomic_load(&flg[tid], __ATOMIC_RELAXED,
                                         __HIP_MEMORY_SCOPE_AGENT) < want) {}
            }
            __syncthreads();
        } else {
            orow[(size_t)t * UU] = h;
        }
    }

    // final state
    out[(size_t)BB * TT * UU + (size_t)gb * UU + gu] = h;
}

extern "C" void kernel_launch(void* const* d_in, const int* in_sizes, int n_in,
                              void* d_out, int out_size, void* d_ws, size_t ws_size,
                              hipStream_t stream) {
    const int* x        = (const int*)d_in[0];
    const float* hidden = (const float*)d_in[1];
    const float* w_in   = (const float*)d_in[2];
    const float* w_rec  = (const float*)d_in[3];
    const float* b_in   = (const float*)d_in[4];
    const float* b_rec  = (const float*)d_in[5];
    float* out          = (float*)d_out;

    unsigned char* ws = (unsigned char*)d_ws;
    uint4* wpack         = (uint4*)ws;                         // 6 MB
    unsigned short* hbuf = (unsigned short*)(ws + 6291456);    // 256 KB
    unsigned int* ctr    = (unsigned int*)(ws + 6553600);      // 1 KB flags

    pack_kernel<<<64, 256, 0, stream>>>(w_rec, wpack);
    seed_kernel<<<256, 256, 0, stream>>>(hidden, hbuf, ctr);
    gru_kernel<<<256, 256, 0, stream>>>(x, hidden, w_in, b_in, b_rec,
                                        wpack, out, hbuf, ctr);
}